// Round 7
// baseline (4282.574 us; speedup 1.0000x reference)
//
#include <hip/hip_runtime.h>

typedef __attribute__((ext_vector_type(8)))  short          bf16x8;
typedef __attribute__((ext_vector_type(4)))  short          bf16x4;
typedef __attribute__((ext_vector_type(16))) float          f32x16;
typedef __attribute__((ext_vector_type(8)))  unsigned int   u32x8;
typedef __attribute__((ext_vector_type(4)))  unsigned short ushort4v;
typedef __attribute__((ext_vector_type(4)))  float          float4v;

#define DEV static __device__ __forceinline__
#define MFMA32(A,B,C) __builtin_amdgcn_mfma_f32_32x32x16_bf16(A,B,C,0,0,0)

// ---- workspace element offsets (unsigned short elements) ----
// WRES: weight tile STREAM in exact consumption order:
//   for st in 0..6: 343 conv tiles (7 layers x 49 taps) + 1 last_w tile
//   = 2408 tiles x 4096 shorts (8KB) each, frag-major [frag(ks*2+mt)][lane][8]
#define NTILES   2408
#define WRES_OFF 0u           // 2408 * 4096                        = 9,863,168
#define FW_OFF   9863168u     // 49 taps * 2 frag * 64 lane * 8     =    50,176
#define P1_OFF   9913344u     // 256 * 2048                         =   524,288
#define P2_OFF   10437632u    // 1792 * 256 (padded rows)           =   458,752
#define ACT0_OFF 10896384u    // 1024 * 64p * 64c                   = 4,194,304
#define PV_OFF   15090688u    // 1024 * 32 * 64                     = 2,097,152
#define HID_OFF  17187840u    // 1024 * 256                         =   262,144
// total 17,449,984 ushorts = 34.9 MB

// ---- d_out offsets (floats) ----
#define VAL_OFF 1740800
#define PID_OFF 1741824

// ---- tower LDS map ----
// acts: rows of 136B (64ch*2B + 8B pad -> b64 reads are 2-way-max = free)
// per image 64*136 = 8704B; double buffered, 4 images. xin/value overlay ACT_B.
#define RS       136
#define IMG_ACT  8704
#define ACT_A    0
#define ACT_B    34816
#define SM_Z     69632
#define SM_BYTES 69888

DEV float bf2f(unsigned short u){ union { unsigned int i; float f; } v; v.i = ((unsigned int)u) << 16; return v.f; }
DEV unsigned short f2bf(float f){
  union { float f; unsigned int i; } v; v.f = f;
  unsigned int x = v.i;
  return (unsigned short)((x + 0x7fffu + ((x >> 16) & 1u)) >> 16);  // RNE
}

// ======================= weight prep =======================
// res_w (7,7,64,64,7,7) f32 -> stream tile (L*49+t+L/7), frag-major:
// element (lane,j) of frag (ks*2+mt) = W[o = mt*32 + (lane&31)][c = ks*16 + (lane>>5)*8 + j]
__global__ void prep_res_k(const float* __restrict__ res_w, unsigned short* __restrict__ ws){
  __shared__ float buf[3136];
  int bx = blockIdx.x;             // L*64 + o
  int L = bx >> 6, o = bx & 63;
  const float* src = res_w + (size_t)bx * 3136;   // (o fixed): [c][dy][dx] contiguous
  for (int e = threadIdx.x; e < 3136; e += 256) buf[e] = src[e];
  __syncthreads();
  unsigned short* dst = ws + WRES_OFF;
  int mt = o >> 5, lrow = o & 31;
  int tilebase = L*49 + L/7;
  for (int e = threadIdx.x; e < 3136; e += 256){
    int t = e >> 6, c = e & 63;
    int ks = c >> 4, hi = (c >> 3) & 1, j = c & 7;
    int lane = hi*32 + lrow;
    dst[(size_t)(tilebase + t)*4096 + ((ks*2 + mt)*64 + lane)*8 + j] = f2bf(buf[c*49 + t]);
  }
}

// first_w -> fw[t][mt][lane][8] (K=16: c = (lane>>5)*8+j, 12 real + 4 zero)
// last_w  -> stream tile (st*344+343), frag-major
// pfc1/pfc2 cast (+pad)
__global__ void prep_misc_k(const float* __restrict__ first_w, const float* __restrict__ last_w,
                            const float* __restrict__ pfc1_w, const float* __restrict__ pfc2_w,
                            unsigned short* __restrict__ ws){
  const int n_fw = 49*1024, n_lw = 28672, n_p1 = 524288, n_p2 = 458752;
  const int total = n_fw + n_lw + n_p1 + n_p2;
  for (int d = blockIdx.x*256 + threadIdx.x; d < total; d += gridDim.x*256){
    if (d < n_fw){
      int t = d >> 10, r = d & 1023;
      int mt = r >> 9, lane = (r >> 3) & 63, j = r & 7;
      int o = mt*32 + (lane & 31);
      int c = ((lane >> 5) << 3) + j;
      float v = (o < 63 && c < 12) ? first_w[(o*12 + c)*49 + t] : 0.f;
      ws[FW_OFF + d] = f2bf(v);
    } else if (d < n_fw + n_lw){
      int e = d - n_fw;
      int st = e >> 12, r = e & 4095;
      int f = r >> 9, lane = (r >> 3) & 63, j = r & 7;
      int ks = f >> 1, mt = f & 1;
      int o = mt*32 + (lane & 31);
      int c = ks*16 + ((lane >> 5) << 3) + j;
      ws[WRES_OFF + (size_t)(st*344 + 343)*4096 + r] = f2bf(last_w[st*4096 + o*64 + c]);
    } else if (d < n_fw + n_lw + n_p1){
      int e = d - n_fw - n_lw; ws[P1_OFF + e] = f2bf(pfc1_w[e]);
    } else {
      int e = d - n_fw - n_lw - n_p1;
      int row = e >> 8, k = e & 255;
      ws[P2_OFF + e] = f2bf(row < 1700 ? pfc2_w[row*256 + k] : 0.f);
    }
  }
}

// ======================= tower =======================

// load this wave's 4 A-frags (frag ks*2+sub, ks=0..3) of one tile (q in shorts)
#define LOADW(W, q) { \
  W[0] = *(const bf16x8*)(q); \
  W[1] = *(const bf16x8*)((q) + 1024); \
  W[2] = *(const bf16x8*)((q) + 2048); \
  W[3] = *(const bf16x8*)((q) + 3072); }

// one conv tap: 8 ds_read_b64 (conflict-free at RS=136) + 4 MFMA into c0
#define TAPB(W, dyc, dxc) { \
  bool v_ = ((unsigned)(py + (dyc) - 3) < 8u) && ((unsigned)(px + (dxc) - 3) < 8u); \
  int pp_ = p + ((dyc) - 3)*8 + ((dxc) - 3); \
  int b_ = (v_ ? rbase + pp_*RS : SM_Z) + hi16; \
  bf16x4 l0 = *(const bf16x4*)(sm + b_); \
  bf16x4 h0 = *(const bf16x4*)(sm + b_ + 8); \
  bf16x4 l1 = *(const bf16x4*)(sm + b_ + 32); \
  bf16x4 h1 = *(const bf16x4*)(sm + b_ + 40); \
  bf16x4 l2 = *(const bf16x4*)(sm + b_ + 64); \
  bf16x4 h2 = *(const bf16x4*)(sm + b_ + 72); \
  bf16x4 l3 = *(const bf16x4*)(sm + b_ + 96); \
  bf16x4 h3 = *(const bf16x4*)(sm + b_ + 104); \
  c0 = MFMA32(W[0], __builtin_shufflevector(l0,h0,0,1,2,3,4,5,6,7), c0); \
  c0 = MFMA32(W[1], __builtin_shufflevector(l1,h1,0,1,2,3,4,5,6,7), c0); \
  c0 = MFMA32(W[2], __builtin_shufflevector(l2,h2,0,1,2,3,4,5,6,7), c0); \
  c0 = MFMA32(W[3], __builtin_shufflevector(l3,h3,0,1,2,3,4,5,6,7), c0); }

#define LBAR() { asm volatile("s_waitcnt lgkmcnt(0)" ::: "memory"); \
                 __builtin_amdgcn_s_barrier(); \
                 asm volatile("" ::: "memory"); }

DEV void conv_epi(const f32x16& acc, int sub, int p, int wb, int hi,
                  unsigned char* smp, const float* sp, const float* bp){
  int rowb = wb + p*RS + sub*64 + hi*8;
  #pragma unroll
  for (int rg = 0; rg < 4; ++rg){
    int o0 = sub*32 + rg*8 + hi*4;
    unsigned short bb[4];
    #pragma unroll
    for (int e = 0; e < 4; ++e){
      float v = sp[o0+e]*acc[rg*4+e] + bp[o0+e];
      v = v > 0.f ? v : 0.f;
      bb[e] = f2bf(v);
    }
    *(ushort4v*)(smp + rowb + rg*16) = ushort4v{bb[0],bb[1],bb[2],bb[3]};
  }
}

DEV void res_epi(const f32x16& acc, u32x8& res, int sub, int p, int wb, int hi,
                 unsigned char* smp, const float* lsp, const float* lbp){
  int rowb = wb + p*RS + sub*64 + hi*8;
  #pragma unroll
  for (int rg = 0; rg < 4; ++rg){
    int o0 = sub*32 + rg*8 + hi*4;
    unsigned short bb[4];
    #pragma unroll
    for (int e = 0; e < 4; ++e){
      unsigned pr = res[rg*2 + (e>>1)];
      float rv = bf2f((unsigned short)((e & 1) ? (pr >> 16) : (pr & 0xffffu)));
      float v = lsp[o0+e]*acc[rg*4+e] + lbp[o0+e] + rv;
      v = v > 0.f ? v : 0.f;
      bb[e] = f2bf(v);
    }
    res[rg*2]   = (unsigned)bb[0] | ((unsigned)bb[1] << 16);
    res[rg*2+1] = (unsigned)bb[2] | ((unsigned)bb[3] << 16);
    *(ushort4v*)(smp + rowb + rg*16) = ushort4v{bb[0],bb[1],bb[2],bb[3]};
  }
}

DEV void first_epi(const f32x16& acc, u32x8& res, int sub, int p, float idsv,
                   int img, int wb, int hi, unsigned char* smp,
                   const float* fsp, const float* fbp, unsigned short* act0){
  int rowb = wb + p*RS + sub*64 + hi*8;
  #pragma unroll
  for (int rg = 0; rg < 4; ++rg){
    int o0 = sub*32 + rg*8 + hi*4;
    unsigned short bb[4];
    #pragma unroll
    for (int e = 0; e < 4; ++e){
      int o = o0 + e;
      int oc = o < 63 ? o : 62;          // avoid OOB load of 63-entry arrays
      float v = fsp[oc]*acc[rg*4+e] + fbp[oc];
      v = v > 0.f ? v : 0.f;
      if (o == 63) v = idsv;             // ids channel, no bn/relu
      bb[e] = f2bf(v);
    }
    res[rg*2]   = (unsigned)bb[0] | ((unsigned)bb[1] << 16);
    res[rg*2+1] = (unsigned)bb[2] | ((unsigned)bb[3] << 16);
    *(ushort4v*)(smp + rowb + rg*16) = ushort4v{bb[0],bb[1],bb[2],bb[3]};
    *(ushort4v*)(act0 + (size_t)img*4096 + p*64 + o0) = ushort4v{bb[0],bb[1],bb[2],bb[3]};
  }
}

__global__ __launch_bounds__(1024, 4) void tower_k(
    const float* __restrict__ x,
    const float* __restrict__ first_s, const float* __restrict__ first_b,
    const float* __restrict__ res_s,   const float* __restrict__ res_b,
    const float* __restrict__ last_s,  const float* __restrict__ last_b,
    const float* __restrict__ vconv_w, const float* __restrict__ v_s, const float* __restrict__ v_b,
    const float* __restrict__ vfc1_w,  const float* __restrict__ vfc1_b,
    const float* __restrict__ vfc2_w,  const float* __restrict__ vfc2_b,
    const unsigned short* __restrict__ ws_r, unsigned short* __restrict__ act0,
    float* __restrict__ value_out)
{
  __shared__ unsigned char sm[SM_BYTES];
  int tid = threadIdx.x, lane = tid & 63, wave = tid >> 6;
  int imgi = wave & 3, sub = (wave >> 2) & 1, pg = wave >> 3;
  int img = blockIdx.x * 4 + imgi;

  for (int i = tid*16; i < SM_BYTES; i += 1024*16) *(float4v*)(sm + i) = float4v{0,0,0,0};
  __syncthreads();

  int col = lane & 31, hi = lane >> 5;
  int hi16 = hi << 4;
  int p  = pg*32 + col;               // my position (0..63)
  int py = p >> 3, px = p & 7;

  // ---- stage x into padded xin (bf16, overlays ACT_B), channels 0..11 ----
  const float* xim = x + (size_t)img * 832;
  int xinbase = ACT_B + imgi * 3584;
  if (wave < 4){
    int q = (lane >> 3)*14 + (lane & 7) + 3;
    for (int c = 0; c < 12; ++c)
      *(unsigned short*)(sm + xinbase + q*32 + c*2) = f2bf(xim[c*64 + lane]);
  }
  float idsv = xim[768 + p];
  __syncthreads();

  // ---- first conv (K=16): wave computes (pg positions, mt=sub) ----
  f32x16 f0 = {};
  const unsigned short* fw = ws_r + FW_OFF;
  int qbx = py*14 + px;
  #pragma unroll
  for (int dy = 0; dy < 7; ++dy){
    bool vy = (unsigned)(py + dy - 3) < 8u;
    int tq = (dy-3)*14;
    #pragma unroll
    for (int dx = 0; dx < 7; ++dx){
      int t = dy*7 + dx;
      bf16x8 a = *(const bf16x8*)(fw + t*1024 + sub*512 + lane*8);
      int q0 = qbx + tq + dx;
      int ba = vy ? (xinbase + q0*32 + hi16) : SM_Z;
      f0 = MFMA32(a, *(const bf16x8*)(sm + ba), f0);
    }
  }
  u32x8 res0;
  first_epi(f0, res0, sub, p, idsv, img, ACT_A + imgi*IMG_ACT, hi, sm,
            first_s, first_b, act0);
  LBAR();

  // ---- residual tower: A global->VGPR (2-deep), B as b64 pairs from RS=136 acts ----
  int rbase = ACT_A + imgi*IMG_ACT;
  int wbase = ACT_B + imgi*IMG_ACT;
  const unsigned short* gw = ws_r + WRES_OFF + sub*512 + lane*8;

  for (int st = 0; st < 7; ++st){
    for (int j = 0; j < 7; ++j){
      int L = st*7 + j;
      f32x16 c0 = {};
      bf16x8 wA[4], wB[4];
      LOADW(wA, gw);
      #pragma unroll
      for (int t = 0; t < 49; ++t){
        const int dy = t / 7, dx = t % 7;
        if ((t & 1) == 0){
          if (t + 1 < 49) LOADW(wB, gw + (t+1)*4096);
          TAPB(wA, dy, dx);
        } else {
          if (t + 1 < 49) LOADW(wA, gw + (t+1)*4096);
          TAPB(wB, dy, dx);
        }
      }
      gw += 49*4096;
      conv_epi(c0, sub, p, wbase, hi, sm, res_s + L*64, res_b + L*64);
      LBAR();
      int tmpb = rbase; rbase = wbase; wbase = tmpb;
    }
    // 1x1 (last_w) + bn + residual + relu
    {
      bf16x8 wA[4];
      LOADW(wA, gw); gw += 4096;
      f32x16 c0 = {};
      {
        int b_ = rbase + p*RS + hi16;
        bf16x4 l0 = *(const bf16x4*)(sm + b_);
        bf16x4 h0 = *(const bf16x4*)(sm + b_ + 8);
        bf16x4 l1 = *(const bf16x4*)(sm + b_ + 32);
        bf16x4 h1 = *(const bf16x4*)(sm + b_ + 40);
        bf16x4 l2 = *(const bf16x4*)(sm + b_ + 64);
        bf16x4 h2 = *(const bf16x4*)(sm + b_ + 72);
        bf16x4 l3 = *(const bf16x4*)(sm + b_ + 96);
        bf16x4 h3 = *(const bf16x4*)(sm + b_ + 104);
        c0 = MFMA32(wA[0], __builtin_shufflevector(l0,h0,0,1,2,3,4,5,6,7), c0);
        c0 = MFMA32(wA[1], __builtin_shufflevector(l1,h1,0,1,2,3,4,5,6,7), c0);
        c0 = MFMA32(wA[2], __builtin_shufflevector(l2,h2,0,1,2,3,4,5,6,7), c0);
        c0 = MFMA32(wA[3], __builtin_shufflevector(l3,h3,0,1,2,3,4,5,6,7), c0);
      }
      res_epi(c0, res0, sub, p, wbase, hi, sm, last_s + st*64, last_b + st*64);
      LBAR();
      int tmpb = rbase; rbase = wbase; wbase = tmpb;
    }
  }

  // ---- value head ----
  float part = 0.f;
  #pragma unroll
  for (int rg = 0; rg < 4; ++rg){
    #pragma unroll
    for (int eh = 0; eh < 2; ++eh){
      unsigned pr = res0[rg*2+eh];
      int ob = sub*32 + rg*8 + hi*4 + eh*2;
      part += bf2f((unsigned short)(pr & 0xffffu))*vconv_w[ob]
            + bf2f((unsigned short)(pr >> 16))*vconv_w[ob+1];
    }
  }
  part += __shfl_xor(part, 32);
  float* vpf = (float*)(sm + ACT_B);           // [imgi][sub][64 pos] (ACT_B dead now)
  if (lane < 32) vpf[(imgi*2 + sub)*64 + pg*32 + lane] = part;
  __syncthreads();

  if (wave < 4){                               // wave w finishes image imgi==w
    int mimg = blockIdx.x*4 + wave;
    float vs = v_s[0], vb = v_b[0];
    float sum = vpf[(wave*2)*64 + lane] + vpf[(wave*2 + 1)*64 + lane];
    float vv = vs*sum + vb; vv = vv > 0.f ? vv : 0.f;
    float* vbuf = (float*)(sm + ACT_B + 2048) + wave*64;
    vbuf[lane] = vv;
    asm volatile("s_waitcnt lgkmcnt(0)" ::: "memory");
    float hidv[4];
    #pragma unroll
    for (int it = 0; it < 4; ++it){
      int jj = it*64 + lane;
      float a = vfc1_b[jj];
      for (int k = 0; k < 64; k += 4){
        float4v vv4 = *(const float4v*)(vbuf + k);
        a += vfc1_w[jj*64+k]*vv4[0] + vfc1_w[jj*64+k+1]*vv4[1]
           + vfc1_w[jj*64+k+2]*vv4[2] + vfc1_w[jj*64+k+3]*vv4[3];
      }
      hidv[it] = a > 0.f ? a : 0.f;
    }
    float tot = 0.f;
    #pragma unroll
    for (int it = 0; it < 4; ++it) tot += hidv[it]*vfc2_w[it*64 + lane];
    #pragma unroll
    for (int off = 32; off; off >>= 1) tot += __shfl_xor(tot, off);
    if (lane == 0) value_out[mimg] = tanhf(tot + vfc2_b[0]);
  }
}

// ======================= gather / piece head =======================
__global__ __launch_bounds__(256) void gather_k(const unsigned short* __restrict__ act0,
                                                unsigned short* __restrict__ pvec,
                                                float* __restrict__ pid_out){
  int lane = threadIdx.x & 63, wave = threadIdx.x >> 6;
  int img = blockIdx.x*4 + wave;
  const unsigned short* arow = act0 + (size_t)img*4096;
  int myid = (int)bf2f(arow[lane*64 + 63]);
  int mypos = 0, mypres = 0;
  for (int p = 0; p < 32; ++p){
    unsigned long long m = __ballot(myid == (p+1));
    if (lane == p){ mypres = (m != 0ull); mypos = mypres ? (__ffsll(m) - 1) : 0; }
  }
  if (lane < 32){
    float v = mypres ? (float)(lane+1) : 0.f;
    #pragma unroll
    for (int s = 0; s < 8; ++s) pid_out[(size_t)img*256 + s*32 + lane] = v;
  }
  for (int p = 0; p < 32; ++p){
    int q  = __shfl(mypos, p);
    int pr = __shfl(mypres, p);
    unsigned short v = pr ? arow[q*64 + lane] : (unsigned short)0;
    pvec[(size_t)img*2048 + p*64 + lane] = v;
  }
}

// ======================= policy head GEMMs =======================
__global__ __launch_bounds__(256) void fc1_k(const unsigned short* __restrict__ pvec,
                                             const unsigned short* __restrict__ w,
                                             const float* __restrict__ bias,
                                             unsigned short* __restrict__ hid){
  int lane = threadIdx.x & 63, wave = threadIdx.x >> 6;
  int col = lane & 31, hi = lane >> 5;
  int wm = wave >> 1, wn = wave & 1;
  int m0 = blockIdx.x*128 + wm*64;
  int n0 = blockIdx.y*128 + wn*64;
  f32x16 a00 = {}, a01 = {}, a10 = {}, a11 = {};
  for (int k = 0; k < 2048; k += 16){
    bf16x8 A0 = *(const bf16x8*)(pvec + (size_t)(m0+col)*2048    + k + hi*8);
    bf16x8 A1 = *(const bf16x8*)(pvec + (size_t)(m0+32+col)*2048 + k + hi*8);
    bf16x8 B0 = *(const bf16x8*)(w + (size_t)(n0+col)*2048    + k + hi*8);
    bf16x8 B1 = *(const bf16x8*)(w + (size_t)(n0+32+col)*2048 + k + hi*8);
    a00 = MFMA32(A0, B0, a00); a01 = MFMA32(A0, B1, a01);
    a10 = MFMA32(A1, B0, a10); a11 = MFMA32(A1, B1, a11);
  }
  #pragma unroll
  for (int mt = 0; mt < 2; ++mt)
    #pragma unroll
    for (int nt = 0; nt < 2; ++nt){
      const f32x16& acc = mt == 0 ? (nt == 0 ? a00 : a01) : (nt == 0 ? a10 : a11);
      int jcol = n0 + nt*32 + col;
      float bj = bias[jcol];
      #pragma unroll
      for (int rg = 0; rg < 4; ++rg)
        #pragma unroll
        for (int e = 0; e < 4; ++e){
          int n = m0 + mt*32 + rg*8 + hi*4 + e;
          float v = acc[rg*4+e] + bj; v = v > 0.f ? v : 0.f;
          hid[(size_t)n*256 + jcol] = f2bf(v);
        }
    }
}

__global__ __launch_bounds__(256) void fc2_k(const unsigned short* __restrict__ hid,
                                             const unsigned short* __restrict__ w,
                                             const float* __restrict__ bias,
                                             float* __restrict__ pol){
  int lane = threadIdx.x & 63, wave = threadIdx.x >> 6;
  int col = lane & 31, hi = lane >> 5;
  int wm = wave >> 1, wn = wave & 1;
  int m0 = blockIdx.x*128 + wm*64;
  int n0 = blockIdx.y*128 + wn*64;
  f32x16 a00 = {}, a01 = {}, a10 = {}, a11 = {};
  for (int k = 0; k < 256; k += 16){
    bf16x8 A0 = *(const bf16x8*)(hid + (size_t)(m0+col)*256    + k + hi*8);
    bf16x8 A1 = *(const bf16x8*)(hid + (size_t)(m0+32+col)*256 + k + hi*8);
    bf16x8 B0 = *(const bf16x8*)(w + (size_t)(n0+col)*256    + k + hi*8);
    bf16x8 B1 = *(const bf16x8*)(w + (size_t)(n0+32+col)*256 + k + hi*8);
    a00 = MFMA32(A0, B0, a00); a01 = MFMA32(A0, B1, a01);
    a10 = MFMA32(A1, B0, a10); a11 = MFMA32(A1, B1, a11);
  }
  #pragma unroll
  for (int mt = 0; mt < 2; ++mt)
    #pragma unroll
    for (int nt = 0; nt < 2; ++nt){
      const f32x16& acc = mt == 0 ? (nt == 0 ? a00 : a01) : (nt == 0 ? a10 : a11);
      int jcol = n0 + nt*32 + col;
      if (jcol < 1700){
        float bj = bias[jcol];
        #pragma unroll
        for (int rg = 0; rg < 4; ++rg)
          #pragma unroll
          for (int e = 0; e < 4; ++e){
            int n = m0 + mt*32 + rg*8 + hi*4 + e;
            pol[(size_t)n*1700 + jcol] = acc[rg*4+e] + bj;
          }
      }
    }
}

// ======================= launch =======================
extern "C" void kernel_launch(void* const* d_in, const int* in_sizes, int n_in,
                              void* d_out, int out_size, void* d_ws, size_t ws_size,
                              hipStream_t stream){
  const float* x       = (const float*)d_in[0];
  const float* first_w = (const float*)d_in[1];
  const float* first_s = (const float*)d_in[2];
  const float* first_b = (const float*)d_in[3];
  const float* res_w   = (const float*)d_in[4];
  const float* res_s   = (const float*)d_in[5];
  const float* res_b   = (const float*)d_in[6];
  const float* last_w  = (const float*)d_in[7];
  const float* last_s  = (const float*)d_in[8];
  const float* last_b  = (const float*)d_in[9];
  const float* pfc1_w  = (const float*)d_in[10];
  const float* pfc1_b  = (const float*)d_in[11];
  const float* pfc2_w  = (const float*)d_in[12];
  const float* pfc2_b  = (const float*)d_in[13];
  const float* vconv_w = (const float*)d_in[14];
  const float* v_s     = (const float*)d_in[15];
  const float* v_b     = (const float*)d_in[16];
  const float* vfc1_w  = (const float*)d_in[17];
  const float* vfc1_b  = (const float*)d_in[18];
  const float* vfc2_w  = (const float*)d_in[19];
  const float* vfc2_b  = (const float*)d_in[20];
  unsigned short* ws = (unsigned short*)d_ws;
  float* out = (float*)d_out;

  prep_res_k <<<3136, 256, 0, stream>>>(res_w, ws);
  prep_misc_k<<<1024, 256, 0, stream>>>(first_w, last_w, pfc1_w, pfc2_w, ws);
  tower_k    <<<256, 1024, 0, stream>>>(x, first_s, first_b, res_s, res_b, last_s, last_b,
                                        vconv_w, v_s, v_b, vfc1_w, vfc1_b, vfc2_w, vfc2_b,
                                        ws, ws + ACT0_OFF, out + VAL_OFF);
  gather_k   <<<256, 256, 0, stream>>>(ws + ACT0_OFF, ws + PV_OFF, out + PID_OFF);
  fc1_k      <<<dim3(8, 2), 256, 0, stream>>>(ws + PV_OFF, ws + P1_OFF, pfc1_b, ws + HID_OFF);
  fc2_k      <<<dim3(8, 14), 256, 0, stream>>>(ws + HID_OFF, ws + P2_OFF, pfc2_b, out);
}

// Round 8
// 2634.381 us; speedup vs baseline: 1.6256x; 1.6256x over previous
//
#include <hip/hip_runtime.h>

typedef __attribute__((ext_vector_type(8)))  short          bf16x8;
typedef __attribute__((ext_vector_type(16))) float          f32x16;
typedef __attribute__((ext_vector_type(8)))  unsigned int   u32x8;
typedef __attribute__((ext_vector_type(4)))  unsigned short ushort4v;
typedef __attribute__((ext_vector_type(4)))  float          float4v;

#define DEV static __device__ __forceinline__
#define MFMA32(A,B,C) __builtin_amdgcn_mfma_f32_32x32x16_bf16(A,B,C,0,0,0)

// ---- workspace element offsets (unsigned short elements) ----
// WRES: weight tile STREAM in exact consumption order:
//   for st in 0..6: 343 conv tiles (7 layers x 49 taps) + 1 last_w tile
//   = 2408 tiles x 4096 shorts (8KB) each, frag-major [frag(ks*2+mt)][lane][8]
#define NTILES   2408
#define WRES_OFF 0u           // 2408 * 4096                        = 9,863,168
#define FW_OFF   9863168u     // 49 taps * 2 frag * 64 lane * 8     =    50,176
#define P1_OFF   9913344u     // 256 * 2048                         =   524,288
#define P2_OFF   10437632u    // 1792 * 256 (padded rows)           =   458,752
#define ACT0_OFF 10896384u    // 1024 * 64p * 64c                   = 4,194,304
#define PV_OFF   15090688u    // 1024 * 32 * 64                     = 2,097,152
#define HID_OFF  17187840u    // 1024 * 256                         =   262,144
// total 17,449,984 ushorts = 34.9 MB

// ---- d_out offsets (floats) ----
#define VAL_OFF 1740800
#define PID_OFF 1741824

// ---- tower LDS map ----
// acts TRANSPOSED: per image [c8-group(8)][pos(64)][16B] = 8192B.
//   B-read per tap = 4 x ds_read_b128 at base+ks*2048, lanes contiguous -> conflict-free.
// double buffered, 4 images. xin staging / value bufs overlay ACT_B (dead then).
#define IMG_ACT  8192
#define ACT_A    0
#define ACT_B    32768
#define SM_Z     65536
#define SM_BYTES 65552

DEV float bf2f(unsigned short u){ union { unsigned int i; float f; } v; v.i = ((unsigned int)u) << 16; return v.f; }
DEV unsigned short f2bf(float f){
  union { float f; unsigned int i; } v; v.f = f;
  unsigned int x = v.i;
  return (unsigned short)((x + 0x7fffu + ((x >> 16) & 1u)) >> 16);  // RNE
}

// ======================= weight prep =======================
// res_w (7,7,64,64,7,7) f32 -> stream tile (L*49+t+L/7), frag-major:
// element (lane,j) of frag (ks*2+mt) = W[o = mt*32 + (lane&31)][c = ks*16 + (lane>>5)*8 + j]
__global__ void prep_res_k(const float* __restrict__ res_w, unsigned short* __restrict__ ws){
  __shared__ float buf[3136];
  int bx = blockIdx.x;             // L*64 + o
  int L = bx >> 6, o = bx & 63;
  const float* src = res_w + (size_t)bx * 3136;   // (o fixed): [c][dy][dx] contiguous
  for (int e = threadIdx.x; e < 3136; e += 256) buf[e] = src[e];
  __syncthreads();
  unsigned short* dst = ws + WRES_OFF;
  int mt = o >> 5, lrow = o & 31;
  int tilebase = L*49 + L/7;
  for (int e = threadIdx.x; e < 3136; e += 256){
    int t = e >> 6, c = e & 63;
    int ks = c >> 4, hi = (c >> 3) & 1, j = c & 7;
    int lane = hi*32 + lrow;
    dst[(size_t)(tilebase + t)*4096 + ((ks*2 + mt)*64 + lane)*8 + j] = f2bf(buf[c*49 + t]);
  }
}

// first_w -> fw[t][mt][lane][8] (K=16: c = (lane>>5)*8+j, 12 real + 4 zero)
// last_w  -> stream tile (st*344+343), frag-major
// pfc1/pfc2 cast (+pad)
__global__ void prep_misc_k(const float* __restrict__ first_w, const float* __restrict__ last_w,
                            const float* __restrict__ pfc1_w, const float* __restrict__ pfc2_w,
                            unsigned short* __restrict__ ws){
  const int n_fw = 49*1024, n_lw = 28672, n_p1 = 524288, n_p2 = 458752;
  const int total = n_fw + n_lw + n_p1 + n_p2;
  for (int d = blockIdx.x*256 + threadIdx.x; d < total; d += gridDim.x*256){
    if (d < n_fw){
      int t = d >> 10, r = d & 1023;
      int mt = r >> 9, lane = (r >> 3) & 63, j = r & 7;
      int o = mt*32 + (lane & 31);
      int c = ((lane >> 5) << 3) + j;
      float v = (o < 63 && c < 12) ? first_w[(o*12 + c)*49 + t] : 0.f;
      ws[FW_OFF + d] = f2bf(v);
    } else if (d < n_fw + n_lw){
      int e = d - n_fw;
      int st = e >> 12, r = e & 4095;
      int f = r >> 9, lane = (r >> 3) & 63, j = r & 7;
      int ks = f >> 1, mt = f & 1;
      int o = mt*32 + (lane & 31);
      int c = ks*16 + ((lane >> 5) << 3) + j;
      ws[WRES_OFF + (size_t)(st*344 + 343)*4096 + r] = f2bf(last_w[st*4096 + o*64 + c]);
    } else if (d < n_fw + n_lw + n_p1){
      int e = d - n_fw - n_lw; ws[P1_OFF + e] = f2bf(pfc1_w[e]);
    } else {
      int e = d - n_fw - n_lw - n_p1;
      int row = e >> 8, k = e & 255;
      ws[P2_OFF + e] = f2bf(row < 1700 ? pfc2_w[row*256 + k] : 0.f);
    }
  }
}

// ======================= tower =======================

// load this wave's 4 A-frags (frag ks*2+sub, ks=0..3) of one tile (q in shorts)
#define LOADW(W, q) { \
  W[0] = *(const bf16x8*)(q); \
  W[1] = *(const bf16x8*)((q) + 1024); \
  W[2] = *(const bf16x8*)((q) + 2048); \
  W[3] = *(const bf16x8*)((q) + 3072); }

// one conv tap: 4 conflict-free ds_read_b128 + 4 MFMA into c0 (dy,dx compile-time)
#define TAPB(W, dyc, dxc) { \
  bool v_ = ((unsigned)(py + (dyc) - 3) < 8u) && ((unsigned)(px + (dxc) - 3) < 8u); \
  int pp_ = p + ((dyc) - 3)*8 + ((dxc) - 3); \
  int b_  = v_ ? (rbase + hi1024 + pp_*16) : SM_Z; \
  int st_ = v_ ? 2048 : 0; \
  c0 = MFMA32(W[0], *(const bf16x8*)(sm + b_),           c0); \
  c0 = MFMA32(W[1], *(const bf16x8*)(sm + b_ + st_),     c0); \
  c0 = MFMA32(W[2], *(const bf16x8*)(sm + b_ + 2*st_),   c0); \
  c0 = MFMA32(W[3], *(const bf16x8*)(sm + b_ + 3*st_),   c0); }

#define LBAR() { asm volatile("s_waitcnt lgkmcnt(0)" ::: "memory"); \
                 __builtin_amdgcn_s_barrier(); \
                 asm volatile("" ::: "memory"); }

DEV void conv_epi(const f32x16& acc, int sub, int p, int wb, int hi,
                  unsigned char* smp, const float* sp, const float* bp){
  // channel group c8 = sub*4+rg, byte offset within 16B chunk = hi*8
  int rowb = wb + p*16 + hi*8 + sub*4096;
  #pragma unroll
  for (int rg = 0; rg < 4; ++rg){
    int o0 = sub*32 + rg*8 + hi*4;
    unsigned short bb[4];
    #pragma unroll
    for (int e = 0; e < 4; ++e){
      float v = sp[o0+e]*acc[rg*4+e] + bp[o0+e];
      v = v > 0.f ? v : 0.f;
      bb[e] = f2bf(v);
    }
    *(ushort4v*)(smp + rowb + rg*1024) = ushort4v{bb[0],bb[1],bb[2],bb[3]};
  }
}

DEV void res_epi(const f32x16& acc, u32x8& res, int sub, int p, int wb, int hi,
                 unsigned char* smp, const float* lsp, const float* lbp){
  int rowb = wb + p*16 + hi*8 + sub*4096;
  #pragma unroll
  for (int rg = 0; rg < 4; ++rg){
    int o0 = sub*32 + rg*8 + hi*4;
    unsigned short bb[4];
    #pragma unroll
    for (int e = 0; e < 4; ++e){
      unsigned pr = res[rg*2 + (e>>1)];
      float rv = bf2f((unsigned short)((e & 1) ? (pr >> 16) : (pr & 0xffffu)));
      float v = lsp[o0+e]*acc[rg*4+e] + lbp[o0+e] + rv;
      v = v > 0.f ? v : 0.f;
      bb[e] = f2bf(v);
    }
    res[rg*2]   = (unsigned)bb[0] | ((unsigned)bb[1] << 16);
    res[rg*2+1] = (unsigned)bb[2] | ((unsigned)bb[3] << 16);
    *(ushort4v*)(smp + rowb + rg*1024) = ushort4v{bb[0],bb[1],bb[2],bb[3]};
  }
}

DEV void first_epi(const f32x16& acc, u32x8& res, int sub, int p, float idsv,
                   int img, int wb, int hi, unsigned char* smp,
                   const float* fsp, const float* fbp, unsigned short* act0){
  int rowb = wb + p*16 + hi*8 + sub*4096;
  #pragma unroll
  for (int rg = 0; rg < 4; ++rg){
    int o0 = sub*32 + rg*8 + hi*4;
    unsigned short bb[4];
    #pragma unroll
    for (int e = 0; e < 4; ++e){
      int o = o0 + e;
      int oc = o < 63 ? o : 62;          // avoid OOB load of 63-entry arrays
      float v = fsp[oc]*acc[rg*4+e] + fbp[oc];
      v = v > 0.f ? v : 0.f;
      if (o == 63) v = idsv;             // ids channel, no bn/relu
      bb[e] = f2bf(v);
    }
    res[rg*2]   = (unsigned)bb[0] | ((unsigned)bb[1] << 16);
    res[rg*2+1] = (unsigned)bb[2] | ((unsigned)bb[3] << 16);
    *(ushort4v*)(smp + rowb + rg*1024) = ushort4v{bb[0],bb[1],bb[2],bb[3]};
    *(ushort4v*)(act0 + (size_t)img*4096 + p*64 + o0) = ushort4v{bb[0],bb[1],bb[2],bb[3]};
  }
}

__global__ __launch_bounds__(1024, 4) void tower_k(
    const float* __restrict__ x,
    const float* __restrict__ first_s, const float* __restrict__ first_b,
    const float* __restrict__ res_s,   const float* __restrict__ res_b,
    const float* __restrict__ last_s,  const float* __restrict__ last_b,
    const float* __restrict__ vconv_w, const float* __restrict__ v_s, const float* __restrict__ v_b,
    const float* __restrict__ vfc1_w,  const float* __restrict__ vfc1_b,
    const float* __restrict__ vfc2_w,  const float* __restrict__ vfc2_b,
    const unsigned short* __restrict__ ws_r, unsigned short* __restrict__ act0,
    float* __restrict__ value_out)
{
  __shared__ unsigned char sm[SM_BYTES];
  int tid = threadIdx.x, lane = tid & 63, wave = tid >> 6;
  int imgi = wave & 3, sub = (wave >> 2) & 1, pg = wave >> 3;
  int img = blockIdx.x * 4 + imgi;

  for (int i = tid*16; i < SM_BYTES; i += 1024*16) *(float4v*)(sm + i) = float4v{0,0,0,0};
  __syncthreads();

  int col = lane & 31, hi = lane >> 5;
  int hi16 = hi << 4;
  int hi1024 = hi << 10;
  int p  = pg*32 + col;               // my position (0..63)
  int py = p >> 3, px = p & 7;

  // ---- stage x into padded xin (bf16, overlays ACT_B), channels 0..11 ----
  const float* xim = x + (size_t)img * 832;
  int xinbase = ACT_B + imgi * 3584;
  if (wave < 4){
    int q = (lane >> 3)*14 + (lane & 7) + 3;
    for (int c = 0; c < 12; ++c)
      *(unsigned short*)(sm + xinbase + q*32 + c*2) = f2bf(xim[c*64 + lane]);
  }
  float idsv = xim[768 + p];
  __syncthreads();

  // ---- first conv (K=16): wave computes (pg positions, mt=sub) ----
  f32x16 f0 = {};
  const unsigned short* fw = ws_r + FW_OFF;
  int qbx = py*14 + px;
  #pragma unroll
  for (int dy = 0; dy < 7; ++dy){
    bool vy = (unsigned)(py + dy - 3) < 8u;
    int tq = (dy-3)*14;
    #pragma unroll
    for (int dx = 0; dx < 7; ++dx){
      int t = dy*7 + dx;
      bf16x8 a = *(const bf16x8*)(fw + t*1024 + sub*512 + lane*8);
      int q0 = qbx + tq + dx;
      int ba = vy ? (xinbase + q0*32 + hi16) : SM_Z;
      f0 = MFMA32(a, *(const bf16x8*)(sm + ba), f0);
    }
  }
  u32x8 res0;
  first_epi(f0, res0, sub, p, idsv, img, ACT_A + imgi*IMG_ACT, hi, sm,
            first_s, first_b, act0);
  LBAR();

  // ---- residual tower: A global->VGPR (2-deep), B 4xb128 from transposed acts ----
  int rbase = ACT_A + imgi*IMG_ACT;
  int wbase = ACT_B + imgi*IMG_ACT;
  const unsigned short* gw = ws_r + WRES_OFF + sub*512 + lane*8;

  for (int st = 0; st < 7; ++st){
    for (int j = 0; j < 7; ++j){
      int L = st*7 + j;
      f32x16 c0 = {};
      bf16x8 wA[4], wB[4];
      LOADW(wA, gw);
      #pragma unroll
      for (int t = 0; t < 49; ++t){
        const int dy = t / 7, dx = t % 7;
        if ((t & 1) == 0){
          if (t + 1 < 49) LOADW(wB, gw + (t+1)*4096);
          TAPB(wA, dy, dx);
        } else {
          if (t + 1 < 49) LOADW(wA, gw + (t+1)*4096);
          TAPB(wB, dy, dx);
        }
      }
      gw += 49*4096;
      conv_epi(c0, sub, p, wbase, hi, sm, res_s + L*64, res_b + L*64);
      LBAR();
      int tmpb = rbase; rbase = wbase; wbase = tmpb;
    }
    // 1x1 (last_w) + bn + residual + relu
    {
      bf16x8 wA[4];
      LOADW(wA, gw); gw += 4096;
      f32x16 c0 = {};
      int b_ = rbase + hi1024 + p*16;
      c0 = MFMA32(wA[0], *(const bf16x8*)(sm + b_),        c0);
      c0 = MFMA32(wA[1], *(const bf16x8*)(sm + b_ + 2048), c0);
      c0 = MFMA32(wA[2], *(const bf16x8*)(sm + b_ + 4096), c0);
      c0 = MFMA32(wA[3], *(const bf16x8*)(sm + b_ + 6144), c0);
      res_epi(c0, res0, sub, p, wbase, hi, sm, last_s + st*64, last_b + st*64);
      LBAR();
      int tmpb = rbase; rbase = wbase; wbase = tmpb;
    }
  }

  // ---- value head ----
  float part = 0.f;
  #pragma unroll
  for (int rg = 0; rg < 4; ++rg){
    #pragma unroll
    for (int eh = 0; eh < 2; ++eh){
      unsigned pr = res0[rg*2+eh];
      int ob = sub*32 + rg*8 + hi*4 + eh*2;
      part += bf2f((unsigned short)(pr & 0xffffu))*vconv_w[ob]
            + bf2f((unsigned short)(pr >> 16))*vconv_w[ob+1];
    }
  }
  part += __shfl_xor(part, 32);
  float* vpf = (float*)(sm + ACT_B);           // [imgi][sub][64 pos] (ACT_B dead now)
  if (lane < 32) vpf[(imgi*2 + sub)*64 + pg*32 + lane] = part;
  __syncthreads();

  if (wave < 4){                               // wave w finishes image imgi==w
    int mimg = blockIdx.x*4 + wave;
    float vs = v_s[0], vb = v_b[0];
    float sum = vpf[(wave*2)*64 + lane] + vpf[(wave*2 + 1)*64 + lane];
    float vv = vs*sum + vb; vv = vv > 0.f ? vv : 0.f;
    float* vbuf = (float*)(sm + ACT_B + 2048) + wave*64;
    vbuf[lane] = vv;
    asm volatile("s_waitcnt lgkmcnt(0)" ::: "memory");
    float hidv[4];
    #pragma unroll
    for (int it = 0; it < 4; ++it){
      int jj = it*64 + lane;
      float a = vfc1_b[jj];
      for (int k = 0; k < 64; k += 4){
        float4v vv4 = *(const float4v*)(vbuf + k);
        a += vfc1_w[jj*64+k]*vv4[0] + vfc1_w[jj*64+k+1]*vv4[1]
           + vfc1_w[jj*64+k+2]*vv4[2] + vfc1_w[jj*64+k+3]*vv4[3];
      }
      hidv[it] = a > 0.f ? a : 0.f;
    }
    float tot = 0.f;
    #pragma unroll
    for (int it = 0; it < 4; ++it) tot += hidv[it]*vfc2_w[it*64 + lane];
    #pragma unroll
    for (int off = 32; off; off >>= 1) tot += __shfl_xor(tot, off);
    if (lane == 0) value_out[mimg] = tanhf(tot + vfc2_b[0]);
  }
}

// ======================= gather / piece head =======================
__global__ __launch_bounds__(256) void gather_k(const unsigned short* __restrict__ act0,
                                                unsigned short* __restrict__ pvec,
                                                float* __restrict__ pid_out){
  int lane = threadIdx.x & 63, wave = threadIdx.x >> 6;
  int img = blockIdx.x*4 + wave;
  const unsigned short* arow = act0 + (size_t)img*4096;
  int myid = (int)bf2f(arow[lane*64 + 63]);
  int mypos = 0, mypres = 0;
  for (int p = 0; p < 32; ++p){
    unsigned long long m = __ballot(myid == (p+1));
    if (lane == p){ mypres = (m != 0ull); mypos = mypres ? (__ffsll(m) - 1) : 0; }
  }
  if (lane < 32){
    float v = mypres ? (float)(lane+1) : 0.f;
    #pragma unroll
    for (int s = 0; s < 8; ++s) pid_out[(size_t)img*256 + s*32 + lane] = v;
  }
  for (int p = 0; p < 32; ++p){
    int q  = __shfl(mypos, p);
    int pr = __shfl(mypres, p);
    unsigned short v = pr ? arow[q*64 + lane] : (unsigned short)0;
    pvec[(size_t)img*2048 + p*64 + lane] = v;
  }
}

// ======================= policy head GEMMs =======================
__global__ __launch_bounds__(256) void fc1_k(const unsigned short* __restrict__ pvec,
                                             const unsigned short* __restrict__ w,
                                             const float* __restrict__ bias,
                                             unsigned short* __restrict__ hid){
  int lane = threadIdx.x & 63, wave = threadIdx.x >> 6;
  int col = lane & 31, hi = lane >> 5;
  int wm = wave >> 1, wn = wave & 1;
  int m0 = blockIdx.x*128 + wm*64;
  int n0 = blockIdx.y*128 + wn*64;
  f32x16 a00 = {}, a01 = {}, a10 = {}, a11 = {};
  for (int k = 0; k < 2048; k += 16){
    bf16x8 A0 = *(const bf16x8*)(pvec + (size_t)(m0+col)*2048    + k + hi*8);
    bf16x8 A1 = *(const bf16x8*)(pvec + (size_t)(m0+32+col)*2048 + k + hi*8);
    bf16x8 B0 = *(const bf16x8*)(w + (size_t)(n0+col)*2048    + k + hi*8);
    bf16x8 B1 = *(const bf16x8*)(w + (size_t)(n0+32+col)*2048 + k + hi*8);
    a00 = MFMA32(A0, B0, a00); a01 = MFMA32(A0, B1, a01);
    a10 = MFMA32(A1, B0, a10); a11 = MFMA32(A1, B1, a11);
  }
  #pragma unroll
  for (int mt = 0; mt < 2; ++mt)
    #pragma unroll
    for (int nt = 0; nt < 2; ++nt){
      const f32x16& acc = mt == 0 ? (nt == 0 ? a00 : a01) : (nt == 0 ? a10 : a11);
      int jcol = n0 + nt*32 + col;
      float bj = bias[jcol];
      #pragma unroll
      for (int rg = 0; rg < 4; ++rg)
        #pragma unroll
        for (int e = 0; e < 4; ++e){
          int n = m0 + mt*32 + rg*8 + hi*4 + e;
          float v = acc[rg*4+e] + bj; v = v > 0.f ? v : 0.f;
          hid[(size_t)n*256 + jcol] = f2bf(v);
        }
    }
}

__global__ __launch_bounds__(256) void fc2_k(const unsigned short* __restrict__ hid,
                                             const unsigned short* __restrict__ w,
                                             const float* __restrict__ bias,
                                             float* __restrict__ pol){
  int lane = threadIdx.x & 63, wave = threadIdx.x >> 6;
  int col = lane & 31, hi = lane >> 5;
  int wm = wave >> 1, wn = wave & 1;
  int m0 = blockIdx.x*128 + wm*64;
  int n0 = blockIdx.y*128 + wn*64;
  f32x16 a00 = {}, a01 = {}, a10 = {}, a11 = {};
  for (int k = 0; k < 256; k += 16){
    bf16x8 A0 = *(const bf16x8*)(hid + (size_t)(m0+col)*256    + k + hi*8);
    bf16x8 A1 = *(const bf16x8*)(hid + (size_t)(m0+32+col)*256 + k + hi*8);
    bf16x8 B0 = *(const bf16x8*)(w + (size_t)(n0+col)*256    + k + hi*8);
    bf16x8 B1 = *(const bf16x8*)(w + (size_t)(n0+32+col)*256 + k + hi*8);
    a00 = MFMA32(A0, B0, a00); a01 = MFMA32(A0, B1, a01);
    a10 = MFMA32(A1, B0, a10); a11 = MFMA32(A1, B1, a11);
  }
  #pragma unroll
  for (int mt = 0; mt < 2; ++mt)
    #pragma unroll
    for (int nt = 0; nt < 2; ++nt){
      const f32x16& acc = mt == 0 ? (nt == 0 ? a00 : a01) : (nt == 0 ? a10 : a11);
      int jcol = n0 + nt*32 + col;
      if (jcol < 1700){
        float bj = bias[jcol];
        #pragma unroll
        for (int rg = 0; rg < 4; ++rg)
          #pragma unroll
          for (int e = 0; e < 4; ++e){
            int n = m0 + mt*32 + rg*8 + hi*4 + e;
            pol[(size_t)n*1700 + jcol] = acc[rg*4+e] + bj;
          }
      }
    }
}

// ======================= launch =======================
extern "C" void kernel_launch(void* const* d_in, const int* in_sizes, int n_in,
                              void* d_out, int out_size, void* d_ws, size_t ws_size,
                              hipStream_t stream){
  const float* x       = (const float*)d_in[0];
  const float* first_w = (const float*)d_in[1];
  const float* first_s = (const float*)d_in[2];
  const float* first_b = (const float*)d_in[3];
  const float* res_w   = (const float*)d_in[4];
  const float* res_s   = (const float*)d_in[5];
  const float* res_b   = (const float*)d_in[6];
  const float* last_w  = (const float*)d_in[7];
  const float* last_s  = (const float*)d_in[8];
  const float* last_b  = (const float*)d_in[9];
  const float* pfc1_w  = (const float*)d_in[10];
  const float* pfc1_b  = (const float*)d_in[11];
  const float* pfc2_w  = (const float*)d_in[12];
  const float* pfc2_b  = (const float*)d_in[13];
  const float* vconv_w = (const float*)d_in[14];
  const float* v_s     = (const float*)d_in[15];
  const float* v_b     = (const float*)d_in[16];
  const float* vfc1_w  = (const float*)d_in[17];
  const float* vfc1_b  = (const float*)d_in[18];
  const float* vfc2_w  = (const float*)d_in[19];
  const float* vfc2_b  = (const float*)d_in[20];
  unsigned short* ws = (unsigned short*)d_ws;
  float* out = (float*)d_out;

  prep_res_k <<<3136, 256, 0, stream>>>(res_w, ws);
  prep_misc_k<<<1024, 256, 0, stream>>>(first_w, last_w, pfc1_w, pfc2_w, ws);
  tower_k    <<<256, 1024, 0, stream>>>(x, first_s, first_b, res_s, res_b, last_s, last_b,
                                        vconv_w, v_s, v_b, vfc1_w, vfc1_b, vfc2_w, vfc2_b,
                                        ws, ws + ACT0_OFF, out + VAL_OFF);
  gather_k   <<<256, 256, 0, stream>>>(ws + ACT0_OFF, ws + PV_OFF, out + PID_OFF);
  fc1_k      <<<dim3(8, 2), 256, 0, stream>>>(ws + PV_OFF, ws + P1_OFF, pfc1_b, ws + HID_OFF);
  fc2_k      <<<dim3(8, 14), 256, 0, stream>>>(ws + HID_OFF, ws + P2_OFF, pfc2_b, out);
}

// Round 9
// 1607.779 us; speedup vs baseline: 2.6637x; 1.6385x over previous
//
#include <hip/hip_runtime.h>

typedef __attribute__((ext_vector_type(8)))  short          bf16x8;
typedef __attribute__((ext_vector_type(16))) float          f32x16;
typedef __attribute__((ext_vector_type(4)))  unsigned int   uint4v;
typedef __attribute__((ext_vector_type(4)))  unsigned short ushort4v;
typedef __attribute__((ext_vector_type(4)))  float          float4v;

#define DEV static __device__ __forceinline__
#define MFMA32(A,B,C) __builtin_amdgcn_mfma_f32_32x32x16_bf16(A,B,C,0,0,0)

// ---- workspace element offsets (unsigned short elements) ----
// WRES: weight tile STREAM: for st 0..6: 49x7 conv tiles + 1 last_w tile
// = 2408 tiles x 4096 shorts, frag-major [frag(ks*2+mt)][lane][8]
#define WRES_OFF 0u
#define FW_OFF   9863168u
#define P1_OFF   9913344u
#define P2_OFF   10437632u
#define ACT0_OFF 10896384u
#define PV_OFF   15090688u
#define HID_OFF  17187840u

// ---- d_out offsets (floats) ----
#define VAL_OFF 1740800
#define PID_OFF 1741824

// ---- tower LDS map: 3 act buffers per image (R5 layout: pos row 128B, XOR swz) ----
#define IMG_AREA 24576          // 3 x 8192
#define SM_Z     98304          // 128B zero row
#define SM_BYTES 98432

DEV float bf2f(unsigned short u){ union { unsigned int i; float f; } v; v.i = ((unsigned int)u) << 16; return v.f; }
DEV unsigned short f2bf(float f){
  union { float f; unsigned int i; } v; v.f = f;
  unsigned int x = v.i;
  return (unsigned short)((x + 0x7fffu + ((x >> 16) & 1u)) >> 16);  // RNE
}

// ======================= weight prep (unchanged layouts) =======================
__global__ void prep_res_k(const float* __restrict__ res_w, unsigned short* __restrict__ ws){
  __shared__ float buf[3136];
  int bx = blockIdx.x;             // L*64 + o
  int L = bx >> 6, o = bx & 63;
  const float* src = res_w + (size_t)bx * 3136;
  for (int e = threadIdx.x; e < 3136; e += 256) buf[e] = src[e];
  __syncthreads();
  unsigned short* dst = ws + WRES_OFF;
  int mt = o >> 5, lrow = o & 31;
  int tilebase = L*49 + L/7;
  for (int e = threadIdx.x; e < 3136; e += 256){
    int t = e >> 6, c = e & 63;
    int ks = c >> 4, hi = (c >> 3) & 1, j = c & 7;
    int lane = hi*32 + lrow;
    dst[(size_t)(tilebase + t)*4096 + ((ks*2 + mt)*64 + lane)*8 + j] = f2bf(buf[c*49 + t]);
  }
}

__global__ void prep_misc_k(const float* __restrict__ first_w, const float* __restrict__ last_w,
                            const float* __restrict__ pfc1_w, const float* __restrict__ pfc2_w,
                            unsigned short* __restrict__ ws){
  const int n_fw = 49*1024, n_lw = 28672, n_p1 = 524288, n_p2 = 458752;
  const int total = n_fw + n_lw + n_p1 + n_p2;
  for (int d = blockIdx.x*256 + threadIdx.x; d < total; d += gridDim.x*256){
    if (d < n_fw){
      int t = d >> 10, r = d & 1023;
      int mt = r >> 9, lane = (r >> 3) & 63, j = r & 7;
      int o = mt*32 + (lane & 31);
      int c = ((lane >> 5) << 3) + j;
      float v = (o < 63 && c < 12) ? first_w[(o*12 + c)*49 + t] : 0.f;
      ws[FW_OFF + d] = f2bf(v);
    } else if (d < n_fw + n_lw){
      int e = d - n_fw;
      int st = e >> 12, r = e & 4095;
      int f = r >> 9, lane = (r >> 3) & 63, j = r & 7;
      int ks = f >> 1, mt = f & 1;
      int o = mt*32 + (lane & 31);
      int c = ks*16 + ((lane >> 5) << 3) + j;
      ws[WRES_OFF + (size_t)(st*344 + 343)*4096 + r] = f2bf(last_w[st*4096 + o*64 + c]);
    } else if (d < n_fw + n_lw + n_p1){
      int e = d - n_fw - n_lw; ws[P1_OFF + e] = f2bf(pfc1_w[e]);
    } else {
      int e = d - n_fw - n_lw - n_p1;
      int row = e >> 8, k = e & 255;
      ws[P2_OFF + e] = f2bf(row < 1700 ? pfc2_w[row*256 + k] : 0.f);
    }
  }
}

// ======================= tower =======================
DEV int baddr(int q, bool valid, int base, int hi16){
  return valid ? (base + (q << 7) + (hi16 ^ ((q & 7) << 4))) : (SM_Z + hi16);
}

#define LBAR() { asm volatile("s_waitcnt lgkmcnt(0)" ::: "memory"); \
                 __builtin_amdgcn_s_barrier(); \
                 asm volatile("" ::: "memory"); }

DEV void packst(unsigned char* sm, int scrb, int lane, int k, const f32x16& A){
  unsigned u[8];
  #pragma unroll
  for (int i = 0; i < 8; ++i)
    u[i] = (unsigned)f2bf(A[2*i]) | ((unsigned)f2bf(A[2*i+1]) << 16);
  uint4v* d = (uint4v*)(sm + scrb + k*2048 + lane*32);
  d[0] = uint4v{u[0],u[1],u[2],u[3]};
  d[1] = uint4v{u[4],u[5],u[6],u[7]};
}
DEV void ldadd(unsigned char* sm, int scrb, int lane, int k, f32x16& A){
  const uint4v* s = (const uint4v*)(sm + scrb + k*2048 + lane*32);
  uint4v a = s[0], b = s[1];
  #pragma unroll
  for (int i = 0; i < 4; ++i){
    A[2*i]   += bf2f((unsigned short)(a[i] & 0xffffu));
    A[2*i+1] += bf2f((unsigned short)(a[i] >> 16));
    A[8+2*i]   += bf2f((unsigned short)(b[i] & 0xffffu));
    A[8+2*i+1] += bf2f((unsigned short)(b[i] >> 16));
  }
}
#define STACC(scrb) { packst(sm,(scrb),lane,0,c00); packst(sm,(scrb),lane,1,c01); \
                      packst(sm,(scrb),lane,2,c10); packst(sm,(scrb),lane,3,c11); }
#define LDADD(scrb) { ldadd(sm,(scrb),lane,0,c00); ldadd(sm,(scrb),lane,1,c01); \
                      ldadd(sm,(scrb),lane,2,c10); ldadd(sm,(scrb),lane,3,c11); }

DEV void conv_epi(const f32x16& acc, int mt, int p, int wb, int hi,
                  unsigned char* smp, const float* sp, const float* bp){
  int swz = (p & 7) << 4; int rowb = wb + (p << 7);
  #pragma unroll
  for (int rg = 0; rg < 4; ++rg){
    int o0 = mt*32 + rg*8 + hi*4;
    unsigned short bb[4];
    #pragma unroll
    for (int e = 0; e < 4; ++e){
      float v = sp[o0+e]*acc[rg*4+e] + bp[o0+e];
      v = v > 0.f ? v : 0.f;
      bb[e] = f2bf(v);
    }
    int ob = mt*64 + rg*16 + hi*8;
    *(ushort4v*)(smp + rowb + (ob ^ swz)) = ushort4v{bb[0],bb[1],bb[2],bb[3]};
  }
}

DEV void res_epi(const f32x16& acc, int mt, int p, int rsb, int wb, int hi,
                 unsigned char* smp, const float* lsp, const float* lbp){
  int swz = (p & 7) << 4;
  int rrow = rsb + (p << 7), wrow = wb + (p << 7);
  #pragma unroll
  for (int rg = 0; rg < 4; ++rg){
    int o0 = mt*32 + rg*8 + hi*4;
    int ob = mt*64 + rg*16 + hi*8;
    ushort4v rv = *(const ushort4v*)(smp + rrow + (ob ^ swz));
    unsigned short bb[4];
    #pragma unroll
    for (int e = 0; e < 4; ++e){
      float v = lsp[o0+e]*acc[rg*4+e] + lbp[o0+e] + bf2f(rv[e]);
      v = v > 0.f ? v : 0.f;
      bb[e] = f2bf(v);
    }
    *(ushort4v*)(smp + wrow + (ob ^ swz)) = ushort4v{bb[0],bb[1],bb[2],bb[3]};
  }
}

DEV void first_epi(const f32x16& acc, int mt, int p, float idsv, int img, int wb, int hi,
                   unsigned char* smp, const float* fsp, const float* fbp,
                   unsigned short* act0){
  int swz = (p & 7) << 4; int rowb = wb + (p << 7);
  #pragma unroll
  for (int rg = 0; rg < 4; ++rg){
    int o0 = mt*32 + rg*8 + hi*4;
    unsigned short bb[4];
    #pragma unroll
    for (int e = 0; e < 4; ++e){
      int o = o0 + e;
      int oc = o < 63 ? o : 62;
      float v = fsp[oc]*acc[rg*4+e] + fbp[oc];
      v = v > 0.f ? v : 0.f;
      if (o == 63) v = idsv;
      bb[e] = f2bf(v);
    }
    int ob = mt*64 + rg*16 + hi*8;
    *(ushort4v*)(smp + rowb + (ob ^ swz)) = ushort4v{bb[0],bb[1],bb[2],bb[3]};
    *(ushort4v*)(act0 + (size_t)img*4096 + p*64 + o0) = ushort4v{bb[0],bb[1],bb[2],bb[3]};
  }
}

__global__ __launch_bounds__(1024, 4) __attribute__((amdgpu_waves_per_eu(4, 4)))
void tower_k(
    const float* __restrict__ x,
    const float* __restrict__ first_s, const float* __restrict__ first_b,
    const float* __restrict__ res_s,   const float* __restrict__ res_b,
    const float* __restrict__ last_s,  const float* __restrict__ last_b,
    const float* __restrict__ vconv_w, const float* __restrict__ v_s, const float* __restrict__ v_b,
    const float* __restrict__ vfc1_w,  const float* __restrict__ vfc1_b,
    const float* __restrict__ vfc2_w,  const float* __restrict__ vfc2_b,
    const unsigned short* __restrict__ ws_r, unsigned short* __restrict__ act0,
    float* __restrict__ value_out)
{
  __shared__ unsigned char sm[SM_BYTES];
  int tid = threadIdx.x, lane = tid & 63, wave = tid >> 6;
  int imgi = wave >> 2, tq = wave & 3;      // wave = (image, tap-quarter)
  int img = blockIdx.x * 4 + imgi;

  for (int i = tid*16; i < SM_BYTES; i += 1024*16) *(float4v*)(sm + i) = float4v{0,0,0,0};
  __syncthreads();

  int col = lane & 31, hi = lane >> 5;
  int hi16 = hi << 4;
  int imgbase = imgi * IMG_AREA;
  int rS = imgbase, rA = imgbase + 8192, rB = imgbase + 16384;

  int p0 = col, p1 = 32 + col;
  int py0 = p0 >> 3, px0 = p0 & 7, py1 = p1 >> 3, px1 = p1 & 7;
  int t0 = tq*12, tend = (tq == 3) ? 49 : (t0 + 12);

  // ---- stage x into padded xin (overlays buf rA), channels 0..11 ----
  const float* xim = x + (size_t)img * 832;
  int xinb = rA;
  if (tq == 0){
    int q = (lane >> 3)*14 + (lane & 7) + 3;
    for (int c = 0; c < 12; ++c)
      *(unsigned short*)(sm + xinb + q*32 + c*2) = f2bf(xim[c*64 + lane]);
  }
  float ids0 = xim[768 + p0];
  float ids1 = xim[768 + p1];
  __syncthreads();

  // ---- first conv (K=16), tap-split; full 64x64 output per wave ----
  {
    f32x16 c00 = {}, c01 = {}, c10 = {}, c11 = {};
    const unsigned short* fw = ws_r + FW_OFF;
    int qbx0 = py0*14 + px0, qbx1 = py1*14 + px1;
    for (int t = t0; t < tend; ++t){
      int dy = (t*37) >> 8, dx = t - dy*7;
      bf16x8 a0 = *(const bf16x8*)(fw + t*1024 +       lane*8);
      bf16x8 a1 = *(const bf16x8*)(fw + t*1024 + 512 + lane*8);
      bool v0 = (unsigned)(py0 + dy - 3) < 8u;
      bool v1 = (unsigned)(py1 + dy - 3) < 8u;
      int q0 = qbx0 + (dy-3)*14 + dx, q1 = qbx1 + (dy-3)*14 + dx;
      bf16x8 B0 = *(const bf16x8*)(sm + (v0 ? (xinb + q0*32 + hi16) : (SM_Z + hi16)));
      bf16x8 B1 = *(const bf16x8*)(sm + (v1 ? (xinb + q1*32 + hi16) : (SM_Z + hi16)));
      c00 = MFMA32(a0, B0, c00); c10 = MFMA32(a1, B0, c10);
      c01 = MFMA32(a0, B1, c01); c11 = MFMA32(a1, B1, c11);
    }
    int scr = rB;
    LBAR();
    if (tq == 3) STACC(scr);
    LBAR();
    if (tq == 2){ LDADD(scr); STACC(scr); }
    LBAR();
    if (tq == 1){ LDADD(scr); STACC(scr); }
    LBAR();
    if (tq == 0){
      LDADD(scr);
      first_epi(c00, 0, p0, ids0, img, rS, hi, sm, first_s, first_b, act0);
      first_epi(c10, 1, p0, ids0, img, rS, hi, sm, first_s, first_b, act0);
      first_epi(c01, 0, p1, ids1, img, rS, hi, sm, first_s, first_b, act0);
      first_epi(c11, 1, p1, ids1, img, rS, hi, sm, first_s, first_b, act0);
    }
    LBAR();
  }

  // ---- residual tower ----
  const unsigned short* wstream = ws_r + WRES_OFF;
  for (int st = 0; st < 7; ++st){
    int rd = rS, wr = rA;
    for (int j = 0; j < 7; ++j){
      int L = st*7 + j;
      const unsigned short* gwL = wstream + (size_t)(st*344 + j*49)*4096 + lane*8;
      f32x16 c00 = {}, c01 = {}, c10 = {}, c11 = {};
      for (int t = t0; t < tend; ++t){
        int dy = (t*37) >> 8, dx = t - dy*7;
        const unsigned short* wt = gwL + (size_t)t*4096;
        bf16x8 wv[8];
        #pragma unroll
        for (int f = 0; f < 8; ++f) wv[f] = *(const bf16x8*)(wt + f*512);
        int off = (dy - 3)*8 + (dx - 3);
        bool v0 = ((unsigned)(py0 + dy - 3) < 8u) && ((unsigned)(px0 + dx - 3) < 8u);
        bool v1 = ((unsigned)(py1 + dy - 3) < 8u) && ((unsigned)(px1 + dx - 3) < 8u);
        int b0 = baddr(p0 + off, v0, rd, hi16);
        int b1 = baddr(p1 + off, v1, rd, hi16);
        #pragma unroll
        for (int ks = 0; ks < 4; ++ks){
          bf16x8 B0 = *(const bf16x8*)(sm + (b0 ^ (ks << 5)));
          bf16x8 B1 = *(const bf16x8*)(sm + (b1 ^ (ks << 5)));
          c00 = MFMA32(wv[ks*2],   B0, c00);
          c10 = MFMA32(wv[ks*2+1], B0, c10);
          c01 = MFMA32(wv[ks*2],   B1, c01);
          c11 = MFMA32(wv[ks*2+1], B1, c11);
        }
      }
      int scr = (j == 0) ? rB : rd;
      LBAR();
      if (tq == 3) STACC(scr);
      LBAR();
      if (tq == 2){ LDADD(scr); STACC(scr); }
      LBAR();
      if (tq == 1){ LDADD(scr); STACC(scr); }
      LBAR();
      if (tq == 0){
        LDADD(scr);
        const float* sp = res_s + L*64;
        const float* bp = res_b + L*64;
        conv_epi(c00, 0, p0, wr, hi, sm, sp, bp);
        conv_epi(c10, 1, p0, wr, hi, sm, sp, bp);
        conv_epi(c01, 0, p1, wr, hi, sm, sp, bp);
        conv_epi(c11, 1, p1, wr, hi, sm, sp, bp);
      }
      LBAR();
      int nrd = wr; wr = (j == 0) ? rB : rd; rd = nrd;
    }
    // 1x1 (last_w) + bn + residual(from rS) + relu -> rB ; only tq0 computes
    if (tq == 0){
      const unsigned short* wt = wstream + (size_t)(st*344 + 343)*4096 + lane*8;
      bf16x8 wv[8];
      #pragma unroll
      for (int f = 0; f < 8; ++f) wv[f] = *(const bf16x8*)(wt + f*512);
      f32x16 c00 = {}, c01 = {}, c10 = {}, c11 = {};
      int b0 = baddr(p0, true, rd, hi16);
      int b1 = baddr(p1, true, rd, hi16);
      #pragma unroll
      for (int ks = 0; ks < 4; ++ks){
        bf16x8 B0 = *(const bf16x8*)(sm + (b0 ^ (ks << 5)));
        bf16x8 B1 = *(const bf16x8*)(sm + (b1 ^ (ks << 5)));
        c00 = MFMA32(wv[ks*2],   B0, c00);
        c10 = MFMA32(wv[ks*2+1], B0, c10);
        c01 = MFMA32(wv[ks*2],   B1, c01);
        c11 = MFMA32(wv[ks*2+1], B1, c11);
      }
      const float* lsp = last_s + st*64;
      const float* lbp = last_b + st*64;
      res_epi(c00, 0, p0, rS, rB, hi, sm, lsp, lbp);
      res_epi(c10, 1, p0, rS, rB, hi, sm, lsp, lbp);
      res_epi(c01, 0, p1, rS, rB, hi, sm, lsp, lbp);
      res_epi(c11, 1, p1, rS, rB, hi, sm, lsp, lbp);
    }
    LBAR();
    int ns = rB; rB = rS; rS = ns;   // new stage input = 1x1 output
  }

  // ---- value head: final acts in rS; tq0 wave of each image finishes it ----
  __syncthreads();
  if (tq == 0){
    float accv = 0.f;
    int rowa = rS + (lane << 7);
    int swz = (lane & 7) << 4;
    #pragma unroll
    for (int k = 0; k < 8; ++k){
      bf16x8 av = *(const bf16x8*)(sm + rowa + ((k*16) ^ swz));
      #pragma unroll
      for (int jj = 0; jj < 8; ++jj)
        accv += bf2f((unsigned short)av[jj]) * vconv_w[k*8 + jj];
    }
    float vv = v_s[0]*accv + v_b[0];
    vv = vv > 0.f ? vv : 0.f;
    float* vbuf = (float*)(sm + rA);
    vbuf[lane] = vv;
    asm volatile("s_waitcnt lgkmcnt(0)" ::: "memory");
    float hidv[4];
    #pragma unroll
    for (int it = 0; it < 4; ++it){
      int jj = it*64 + lane;
      float a = vfc1_b[jj];
      for (int k = 0; k < 64; k += 4){
        float4v v4 = *(const float4v*)(vbuf + k);
        a += vfc1_w[jj*64+k]*v4[0] + vfc1_w[jj*64+k+1]*v4[1]
           + vfc1_w[jj*64+k+2]*v4[2] + vfc1_w[jj*64+k+3]*v4[3];
      }
      hidv[it] = a > 0.f ? a : 0.f;
    }
    float tot = 0.f;
    #pragma unroll
    for (int it = 0; it < 4; ++it) tot += hidv[it]*vfc2_w[it*64 + lane];
    #pragma unroll
    for (int off = 32; off; off >>= 1) tot += __shfl_xor(tot, off);
    if (lane == 0) value_out[img] = tanhf(tot + vfc2_b[0]);
  }
}

// ======================= gather / piece head =======================
__global__ __launch_bounds__(256) void gather_k(const unsigned short* __restrict__ act0,
                                                unsigned short* __restrict__ pvec,
                                                float* __restrict__ pid_out){
  int lane = threadIdx.x & 63, wave = threadIdx.x >> 6;
  int img = blockIdx.x*4 + wave;
  const unsigned short* arow = act0 + (size_t)img*4096;
  int myid = (int)bf2f(arow[lane*64 + 63]);
  int mypos = 0, mypres = 0;
  for (int p = 0; p < 32; ++p){
    unsigned long long m = __ballot(myid == (p+1));
    if (lane == p){ mypres = (m != 0ull); mypos = mypres ? (__ffsll(m) - 1) : 0; }
  }
  if (lane < 32){
    float v = mypres ? (float)(lane+1) : 0.f;
    #pragma unroll
    for (int s = 0; s < 8; ++s) pid_out[(size_t)img*256 + s*32 + lane] = v;
  }
  for (int p = 0; p < 32; ++p){
    int q  = __shfl(mypos, p);
    int pr = __shfl(mypres, p);
    unsigned short v = pr ? arow[q*64 + lane] : (unsigned short)0;
    pvec[(size_t)img*2048 + p*64 + lane] = v;
  }
}

// ======================= policy head GEMMs =======================
__global__ __launch_bounds__(256) void fc1_k(const unsigned short* __restrict__ pvec,
                                             const unsigned short* __restrict__ w,
                                             const float* __restrict__ bias,
                                             unsigned short* __restrict__ hid){
  int lane = threadIdx.x & 63, wave = threadIdx.x >> 6;
  int col = lane & 31, hi = lane >> 5;
  int wm = wave >> 1, wn = wave & 1;
  int m0 = blockIdx.x*128 + wm*64;
  int n0 = blockIdx.y*128 + wn*64;
  f32x16 a00 = {}, a01 = {}, a10 = {}, a11 = {};
  for (int k = 0; k < 2048; k += 16){
    bf16x8 A0 = *(const bf16x8*)(pvec + (size_t)(m0+col)*2048    + k + hi*8);
    bf16x8 A1 = *(const bf16x8*)(pvec + (size_t)(m0+32+col)*2048 + k + hi*8);
    bf16x8 B0 = *(const bf16x8*)(w + (size_t)(n0+col)*2048    + k + hi*8);
    bf16x8 B1 = *(const bf16x8*)(w + (size_t)(n0+32+col)*2048 + k + hi*8);
    a00 = MFMA32(A0, B0, a00); a01 = MFMA32(A0, B1, a01);
    a10 = MFMA32(A1, B0, a10); a11 = MFMA32(A1, B1, a11);
  }
  #pragma unroll
  for (int mt = 0; mt < 2; ++mt)
    #pragma unroll
    for (int nt = 0; nt < 2; ++nt){
      const f32x16& acc = mt == 0 ? (nt == 0 ? a00 : a01) : (nt == 0 ? a10 : a11);
      int jcol = n0 + nt*32 + col;
      float bj = bias[jcol];
      #pragma unroll
      for (int rg = 0; rg < 4; ++rg)
        #pragma unroll
        for (int e = 0; e < 4; ++e){
          int n = m0 + mt*32 + rg*8 + hi*4 + e;
          float v = acc[rg*4+e] + bj; v = v > 0.f ? v : 0.f;
          hid[(size_t)n*256 + jcol] = f2bf(v);
        }
    }
}

__global__ __launch_bounds__(256) void fc2_k(const unsigned short* __restrict__ hid,
                                             const unsigned short* __restrict__ w,
                                             const float* __restrict__ bias,
                                             float* __restrict__ pol){
  int lane = threadIdx.x & 63, wave = threadIdx.x >> 6;
  int col = lane & 31, hi = lane >> 5;
  int wm = wave >> 1, wn = wave & 1;
  int m0 = blockIdx.x*128 + wm*64;
  int n0 = blockIdx.y*128 + wn*64;
  f32x16 a00 = {}, a01 = {}, a10 = {}, a11 = {};
  for (int k = 0; k < 256; k += 16){
    bf16x8 A0 = *(const bf16x8*)(hid + (size_t)(m0+col)*256    + k + hi*8);
    bf16x8 A1 = *(const bf16x8*)(hid + (size_t)(m0+32+col)*256 + k + hi*8);
    bf16x8 B0 = *(const bf16x8*)(w + (size_t)(n0+col)*256    + k + hi*8);
    bf16x8 B1 = *(const bf16x8*)(w + (size_t)(n0+32+col)*256 + k + hi*8);
    a00 = MFMA32(A0, B0, a00); a01 = MFMA32(A0, B1, a01);
    a10 = MFMA32(A1, B0, a10); a11 = MFMA32(A1, B1, a11);
  }
  #pragma unroll
  for (int mt = 0; mt < 2; ++mt)
    #pragma unroll
    for (int nt = 0; nt < 2; ++nt){
      const f32x16& acc = mt == 0 ? (nt == 0 ? a00 : a01) : (nt == 0 ? a10 : a11);
      int jcol = n0 + nt*32 + col;
      if (jcol < 1700){
        float bj = bias[jcol];
        #pragma unroll
        for (int rg = 0; rg < 4; ++rg)
          #pragma unroll
          for (int e = 0; e < 4; ++e){
            int n = m0 + mt*32 + rg*8 + hi*4 + e;
            pol[(size_t)n*1700 + jcol] = acc[rg*4+e] + bj;
          }
      }
    }
}

// ======================= launch =======================
extern "C" void kernel_launch(void* const* d_in, const int* in_sizes, int n_in,
                              void* d_out, int out_size, void* d_ws, size_t ws_size,
                              hipStream_t stream){
  const float* x       = (const float*)d_in[0];
  const float* first_w = (const float*)d_in[1];
  const float* first_s = (const float*)d_in[2];
  const float* first_b = (const float*)d_in[3];
  const float* res_w   = (const float*)d_in[4];
  const float* res_s   = (const float*)d_in[5];
  const float* res_b   = (const float*)d_in[6];
  const float* last_w  = (const float*)d_in[7];
  const float* last_s  = (const float*)d_in[8];
  const float* last_b  = (const float*)d_in[9];
  const float* pfc1_w  = (const float*)d_in[10];
  const float* pfc1_b  = (const float*)d_in[11];
  const float* pfc2_w  = (const float*)d_in[12];
  const float* pfc2_b  = (const float*)d_in[13];
  const float* vconv_w = (const float*)d_in[14];
  const float* v_s     = (const float*)d_in[15];
  const float* v_b     = (const float*)d_in[16];
  const float* vfc1_w  = (const float*)d_in[17];
  const float* vfc1_b  = (const float*)d_in[18];
  const float* vfc2_w  = (const float*)d_in[19];
  const float* vfc2_b  = (const float*)d_in[20];
  unsigned short* ws = (unsigned short*)d_ws;
  float* out = (float*)d_out;

  prep_res_k <<<3136, 256, 0, stream>>>(res_w, ws);
  prep_misc_k<<<1024, 256, 0, stream>>>(first_w, last_w, pfc1_w, pfc2_w, ws);
  tower_k    <<<256, 1024, 0, stream>>>(x, first_s, first_b, res_s, res_b, last_s, last_b,
                                        vconv_w, v_s, v_b, vfc1_w, vfc1_b, vfc2_w, vfc2_b,
                                        ws, ws + ACT0_OFF, out + VAL_OFF);
  gather_k   <<<256, 256, 0, stream>>>(ws + ACT0_OFF, ws + PV_OFF, out + PID_OFF);
  fc1_k      <<<dim3(8, 2), 256, 0, stream>>>(ws + PV_OFF, ws + P1_OFF, pfc1_b, ws + HID_OFF);
  fc2_k      <<<dim3(8, 14), 256, 0, stream>>>(ws + HID_OFF, ws + P2_OFF, pfc2_b, out);
}